// Round 13
// baseline (78.205 us; speedup 1.0000x reference)
//
#include <hip/hip_runtime.h>
#include <math.h>

#define Nn 8192
#define Dd 256
#define Kk 32

typedef float        f4x __attribute__((ext_vector_type(4)));
typedef unsigned int u2x __attribute__((ext_vector_type(2)));

// ws layout:
// [0, 2097152 floats)  P'[gh][blk][w][k][d16]  bf16 2*256*16*32*16 (8 MB, nt-streamed)
//   elem off (bf16) = gh*2097152 + blk*8192 + w*512 + k*16 + d16   (d = w*16+d16)
// [2228224, 2236416)   Sp[k][blk] f32 32*256   (per-block gamma sums)
#define SP_OFF  2228224

__device__ __forceinline__ unsigned bfpack(float a, float b) {   // RNE bf16 pair
    unsigned ua = __float_as_uint(a); ua += 0x7FFFu + ((ua >> 16) & 1u);
    unsigned ub = __float_as_uint(b); ub += 0x7FFFu + ((ub >> 16) & 1u);
    return (ua >> 16) | (ub & 0xFFFF0000u);
}
__device__ __forceinline__ void nt_store_bf4(unsigned short* p, f4x v) {
    u2x d2; d2.x = bfpack(v.x, v.y); d2.y = bfpack(v.z, v.w);
    __builtin_nontemporal_store(d2, (u2x*)p);                    // 8 B nt store
}
__device__ __forceinline__ float bflo(unsigned u) { return __uint_as_float(u << 16); }
__device__ __forceinline__ float bfhi(unsigned u) { return __uint_as_float(u & 0xFFFF0000u); }

// K1: gamma + partial G/H. Accumulate relayout: wave owns d-slice [16w,16w+16),
// lane=(k16,dq) -> x read is a 4-address broadcast (64 B/wave/r vs 1 KB dense),
// gamma read is one paired b64. gS layout: [r][k16][2] = (gam[r][k16],gam[r][k16+16]).
__global__ __launch_bounds__(1024) void fused_kernel(const float* __restrict__ x,
                                                     const float* __restrict__ w,
                                                     const float* __restrict__ b,
                                                     float* __restrict__ ws,
                                                     float* __restrict__ out) {
    __shared__ __align__(16) float4 uS4[64 * 33];   // ~33.8 KB transposed pad+1
    __shared__ __align__(16) float4 vS4[64 * 33];   // ~33.8 KB
    __shared__ __align__(16) float4 xS4[32 * 64];   // 32 KB linear (DMA dest)
    __shared__ float  gS[1024];                     // gamma [r][k16][2] 4 KB

    float* Sp = ws + SP_OFF;
    int tid = threadIdx.x;
    int blk = blockIdx.x;

    // ---- zero the output accumulators (stream order covers K2's atomics) ----
    if (tid < 64) out[blk * 64 + tid] = 0.f;

    // ---- async DMA: x tile -> LDS (completes at the barrier) ----
    {
        const float* xg = x + (size_t)blk * 32 * Dd;
        #pragma unroll
        for (int i = 0; i < 2; ++i) {
            int e4 = tid + i * 1024;
            __builtin_amdgcn_global_load_lds(
                (const __attribute__((address_space(1))) void*)(xg + (size_t)e4 * 4),
                (__attribute__((address_space(3))) void*)(&xS4[e4]),
                16, 0, 0);
        }
    }

    // ---- stage + transpose w, w*b into LDS (overlaps the x DMA) ----
    {
        const float4* w4 = (const float4*)w;
        const float4* b4 = (const float4*)b;
        #pragma unroll
        for (int i = 0; i < 2; ++i) {
            int e4 = tid + i * 1024;
            int k  = e4 >> 6;
            int d4 = e4 & 63;
            float4 wv = w4[e4];
            float4 bv = b4[e4];
            float4 vv = {wv.x * bv.x, wv.y * bv.y, wv.z * bv.z, wv.w * bv.w};
            uS4[d4 * 33 + k] = wv;
            vS4[d4 * 33 + k] = vv;
        }
    }
    __syncthreads();                          // drains vmcnt -> x DMA done too

    // ---- gamma: 16 waves x 2 rows; u,v,x all from LDS ----
    {
        int lane = tid & 63;
        int wave = tid >> 6;
        int k = lane & 31;
        int h = lane >> 5;
        int r0 = wave * 2;

        const float4* xr0 = &xS4[(r0 + 0) * 64];
        const float4* xr1 = &xS4[(r0 + 1) * 64];

        float4 a0 = {0.f, 0.f, 0.f, 0.f}, a1 = a0;

        #pragma unroll 8
        for (int i = 0; i < 32; ++i) {
            int ii = h * 32 + i;
            float4 u  = uS4[ii * 33 + k];
            float4 v  = vS4[ii * 33 + k];
            float4 x0 = xr0[ii];             // LDS broadcast within half-wave
            float4 x1 = xr1[ii];
            float y;
            y = fmaf(u.x, x0.x, v.x); a0.x = fmaf(y, y, a0.x);
            y = fmaf(u.y, x0.y, v.y); a0.y = fmaf(y, y, a0.y);
            y = fmaf(u.z, x0.z, v.z); a0.z = fmaf(y, y, a0.z);
            y = fmaf(u.w, x0.w, v.w); a0.w = fmaf(y, y, a0.w);
            y = fmaf(u.x, x1.x, v.x); a1.x = fmaf(y, y, a1.x);
            y = fmaf(u.y, x1.y, v.y); a1.y = fmaf(y, y, a1.y);
            y = fmaf(u.z, x1.z, v.z); a1.z = fmaf(y, y, a1.z);
            y = fmaf(u.w, x1.w, v.w); a1.w = fmaf(y, y, a1.w);
        }

        float s0 = (a0.x + a0.y) + (a0.z + a0.w);
        float s1 = (a1.x + a1.y) + (a1.z + a1.w);
        s0 += __shfl_xor(s0, 32);            // combine the two d-halves
        s1 += __shfl_xor(s1, 32);
        float y40 = -0.5f * s0, y41 = -0.5f * s1;

        float m0 = y40, m1 = y41;
        #pragma unroll
        for (int o = 16; o >= 1; o >>= 1) {
            m0 = fmaxf(m0, __shfl_xor(m0, o));
            m1 = fmaxf(m1, __shfl_xor(m1, o));
        }
        float e0 = __expf(y40 - m0), e1 = __expf(y41 - m1);
        float t0 = e0, t1 = e1;
        #pragma unroll
        for (int o = 16; o >= 1; o >>= 1) {
            t0 += __shfl_xor(t0, o);
            t1 += __shfl_xor(t1, o);
        }
        if (h == 0) {
            int kk = (k & 15) * 2 + (k >> 4);           // paired layout
            gS[(r0 + 0) * 32 + kk] = e0 / t0;
            gS[(r0 + 1) * 32 + kk] = e1 / t1;
        }
    }
    __syncthreads();

    // ---- per-block gamma sums -> Sp[k][blk] ----
    if (tid < 32) {
        int kk = (tid & 15) * 2 + (tid >> 4);
        float s0 = 0.f, s1 = 0.f, s2 = 0.f, s3 = 0.f;
        #pragma unroll
        for (int r = 0; r < 32; r += 4) {
            s0 += gS[(r + 0) * 32 + kk];
            s1 += gS[(r + 1) * 32 + kk];
            s2 += gS[(r + 2) * 32 + kk];
            s3 += gS[(r + 3) * 32 + kk];
        }
        Sp[tid * 256 + blk] = (s0 + s1) + (s2 + s3);
    }

    // ---- accumulate: wave = d-slice, lane = (k16, dq) ----
    {
        int lane = tid & 63;
        int wave = tid >> 6;                 // d-slice [16w, 16w+16)
        int k16 = lane >> 2;                 // 0..15
        int dq  = lane & 3;                  // f4 column within slice
        const f4x* xl4 = (const f4x*)xS4;
        const float2* gP = (const float2*)gS;   // [r][k16] -> (g[k16], g[k16+16])

        f4x aG0 = {0.f, 0.f, 0.f, 0.f}, aH0 = aG0, aG1 = aG0, aH1 = aG0;

        #pragma unroll 4
        for (int r = 0; r < 32; ++r) {
            f4x xv = xl4[r * 64 + wave * 4 + dq];   // 4-address broadcast
            f4x xx = xv * xv;
            float2 g2 = gP[r * 16 + k16];           // paired b64
            aG0 += g2.x * xv;  aH0 += g2.x * xx;
            aG1 += g2.y * xv;  aH1 += g2.y * xx;
        }

        // P' store: per (gh, k-half) one contiguous 512 B wave-store
        unsigned short* Pb = (unsigned short*)ws;
        size_t base = ((size_t)blk * 16 + wave) * 512;        // gh=0, elem units
        const size_t GHS = (size_t)2097152;                   // gh stride (elems)
        int o0 = k16 * 16 + dq * 4;                           // k = k16
        int o1 = (k16 + 16) * 16 + dq * 4;                    // k = k16+16
        nt_store_bf4(Pb + base + o0,        aG0);
        nt_store_bf4(Pb + base + o1,        aG1);
        nt_store_bf4(Pb + base + GHS + o0,  aH0);
        nt_store_bf4(Pb + base + GHS + o1,  aH1);
    }
}

// K2 (final): 512 blocks x 256 thr; block (gh, w, c) reduces blk ∈ [16c,16c+16)
// of its [32k x 16d] tile and atomically adds the final-scaled contribution to
// out. Blocks (gh=0, c=0) also fold in the sv terms. Stream order only.
__global__ __launch_bounds__(256) void red_final(const float* __restrict__ w,
                                                 const float* __restrict__ b,
                                                 const float* __restrict__ ws,
                                                 float* __restrict__ out) {
    const unsigned* P32 = (const unsigned*)ws;   // 2 bf16 per word
    const float* Sp = ws + SP_OFF;
    int tid = threadIdx.x;
    int bid = blockIdx.x;
    int gh  = bid >> 8;
    int wsl = (bid >> 4) & 15;               // d-slice
    int c   = bid & 15;                      // blk chunk

    // thread covers elems e=2tid, 2tid+1 of the 512-elem tile (k = tid>>3)
    size_t off = (size_t)gh * 1048576 + (size_t)(c * 16) * 4096 + wsl * 256 + tid;
    float s0 = 0.f, s1 = 0.f;
    #pragma unroll
    for (int j = 0; j < 16; ++j) {
        unsigned v = __builtin_nontemporal_load(&P32[off + (size_t)j * 4096]);
        s0 += bflo(v);
        s1 += bfhi(v);
    }

    int k  = tid >> 3;
    int d0 = (tid * 2) & 15;
    int idx0 = k * Dd + wsl * 16 + d0;       // and idx0+1
    float wv0 = w[idx0], wv1 = w[idx0 + 1];
    float bv0 = b[idx0], bv1 = b[idx0 + 1];
    const float invN = 1.0f / 8192.0f;
    const float c2 = 0.70710678118654752440f * invN;   // 1/(sqrt(2)*N)
    float w20 = wv0 * wv0, w21 = wv1 * wv1;

    float sg0, sg1, mu0 = 0.f, mu1 = 0.f;
    if (gh == 0) {                            // s = G-chunk
        mu0 = wv0 * s0 * invN;         mu1 = wv1 * s1 * invN;
        sg0 = w20 * 2.0f * bv0 * s0 * c2;  sg1 = w21 * 2.0f * bv1 * s1 * c2;
    } else {                                  // s = H-chunk
        sg0 = w20 * s0 * c2;           sg1 = w21 * s1 * c2;
    }

    if (gh == 0 && c == 0) {                  // fold sv terms (once per (k,d))
        int j = tid & 7;
        float acc = 0.f;
        #pragma unroll 8
        for (int i = 0; i < 32; ++i) acc += Sp[k * 256 + j * 32 + i];
        acc += __shfl_xor(acc, 1);
        acc += __shfl_xor(acc, 2);
        acc += __shfl_xor(acc, 4);            // sv for this k (8-lane group)
        sg0 += (w20 * bv0 * bv0 - 1.0f) * acc * c2;
        sg1 += (w21 * bv1 * bv1 - 1.0f) * acc * c2;
        mu0 += wv0 * bv0 * acc * invN;
        mu1 += wv1 * bv1 * acc * invN;
    }

    atomicAdd(&out[idx0],     sg0);           // sigma_part
    atomicAdd(&out[idx0 + 1], sg1);
    if (gh == 0) {
        atomicAdd(&out[Kk * Dd + idx0],     mu0);   // mu_part
        atomicAdd(&out[Kk * Dd + idx0 + 1], mu1);
    }
}

extern "C" void kernel_launch(void* const* d_in, const int* in_sizes, int n_in,
                              void* d_out, int out_size, void* d_ws, size_t ws_size,
                              hipStream_t stream) {
    const float* x = (const float*)d_in[0];
    const float* w = (const float*)d_in[1];
    const float* b = (const float*)d_in[2];
    float* out = (float*)d_out;
    float* ws = (float*)d_ws;

    hipLaunchKernelGGL(fused_kernel, dim3(256), dim3(1024), 0, stream, x, w, b, ws, out);
    hipLaunchKernelGGL(red_final,    dim3(512), dim3(256),  0, stream, w, b, ws, out);
}

// Round 14
// 76.118 us; speedup vs baseline: 1.0274x; 1.0274x over previous
//
#include <hip/hip_runtime.h>
#include <math.h>

#define Nn 8192
#define Dd 256
#define Kk 32

typedef float        f4x __attribute__((ext_vector_type(4)));
typedef unsigned int u2x __attribute__((ext_vector_type(2)));
typedef unsigned int u4x __attribute__((ext_vector_type(4)));

// ws layout:
// [0,        2097152)  P[k][gh][blk][d]  bf16 32*2*256*256 (8 MB partials, nt-streamed)
// [2228224,  2236416)  Sp[k][blk]        f32  32*256       (per-block gamma sums)
#define SP_OFF  2228224

__device__ __forceinline__ unsigned bfpack(float a, float b) {   // RNE bf16 pair
    unsigned ua = __float_as_uint(a); ua += 0x7FFFu + ((ua >> 16) & 1u);
    unsigned ub = __float_as_uint(b); ub += 0x7FFFu + ((ub >> 16) & 1u);
    return (ua >> 16) | (ub & 0xFFFF0000u);
}
__device__ __forceinline__ void nt_store_bf4(unsigned short* p, f4x v) {
    u2x d2; d2.x = bfpack(v.x, v.y); d2.y = bfpack(v.z, v.w);
    __builtin_nontemporal_store(d2, (u2x*)p);                    // 8 B nt store
}
__device__ __forceinline__ float bflo(unsigned u) { return __uint_as_float(u << 16); }
__device__ __forceinline__ float bfhi(unsigned u) { return __uint_as_float(u & 0xFFFF0000u); }

// K1: fused gamma + partial G/H (R11 body) + zeroing of `out` (64 floats/block;
// stream order guarantees visibility before K2's atomics).
__global__ __launch_bounds__(1024) void fused_kernel(const float* __restrict__ x,
                                                     const float* __restrict__ w,
                                                     const float* __restrict__ b,
                                                     float* __restrict__ ws,
                                                     float* __restrict__ out) {
    __shared__ __align__(16) float4 uS4[64 * 33];   // ~33.8 KB transposed pad+1
    __shared__ __align__(16) float4 vS4[64 * 33];   // ~33.8 KB
    __shared__ __align__(16) float4 xS4[32 * 64];   // 32 KB linear (DMA dest)
    __shared__ float  gS[1024];                     // gamma [r][k] 4 KB

    float* Sp = ws + SP_OFF;
    int tid = threadIdx.x;
    int blk = blockIdx.x;

    // ---- zero the output accumulators (2*32*256 = 16384 floats / 256 blocks) ----
    if (tid < 64) out[blk * 64 + tid] = 0.f;

    // ---- async DMA: x tile -> LDS (completes at the barrier) ----
    {
        const float* xg = x + (size_t)blk * 32 * Dd;
        #pragma unroll
        for (int i = 0; i < 2; ++i) {
            int e4 = tid + i * 1024;
            __builtin_amdgcn_global_load_lds(
                (const __attribute__((address_space(1))) void*)(xg + (size_t)e4 * 4),
                (__attribute__((address_space(3))) void*)(&xS4[e4]),
                16, 0, 0);
        }
    }

    // ---- stage + transpose w, w*b into LDS (overlaps the x DMA) ----
    {
        const float4* w4 = (const float4*)w;
        const float4* b4 = (const float4*)b;
        #pragma unroll
        for (int i = 0; i < 2; ++i) {
            int e4 = tid + i * 1024;
            int k  = e4 >> 6;
            int d4 = e4 & 63;
            float4 wv = w4[e4];
            float4 bv = b4[e4];
            float4 vv = {wv.x * bv.x, wv.y * bv.y, wv.z * bv.z, wv.w * bv.w};
            uS4[d4 * 33 + k] = wv;
            vS4[d4 * 33 + k] = vv;
        }
    }
    __syncthreads();                          // drains vmcnt -> x DMA done too

    // ---- gamma: 16 waves x 2 rows; u,v,x all from LDS ----
    {
        int lane = tid & 63;
        int wave = tid >> 6;
        int k = lane & 31;
        int h = lane >> 5;
        int r0 = wave * 2;

        const float4* xr0 = &xS4[(r0 + 0) * 64];
        const float4* xr1 = &xS4[(r0 + 1) * 64];

        float4 a0 = {0.f, 0.f, 0.f, 0.f}, a1 = a0;

        #pragma unroll 8
        for (int i = 0; i < 32; ++i) {
            int ii = h * 32 + i;
            float4 u  = uS4[ii * 33 + k];
            float4 v  = vS4[ii * 33 + k];
            float4 x0 = xr0[ii];             // LDS broadcast within half-wave
            float4 x1 = xr1[ii];
            float y;
            y = fmaf(u.x, x0.x, v.x); a0.x = fmaf(y, y, a0.x);
            y = fmaf(u.y, x0.y, v.y); a0.y = fmaf(y, y, a0.y);
            y = fmaf(u.z, x0.z, v.z); a0.z = fmaf(y, y, a0.z);
            y = fmaf(u.w, x0.w, v.w); a0.w = fmaf(y, y, a0.w);
            y = fmaf(u.x, x1.x, v.x); a1.x = fmaf(y, y, a1.x);
            y = fmaf(u.y, x1.y, v.y); a1.y = fmaf(y, y, a1.y);
            y = fmaf(u.z, x1.z, v.z); a1.z = fmaf(y, y, a1.z);
            y = fmaf(u.w, x1.w, v.w); a1.w = fmaf(y, y, a1.w);
        }

        float s0 = (a0.x + a0.y) + (a0.z + a0.w);
        float s1 = (a1.x + a1.y) + (a1.z + a1.w);
        s0 += __shfl_xor(s0, 32);            // combine the two d-halves
        s1 += __shfl_xor(s1, 32);
        float y40 = -0.5f * s0, y41 = -0.5f * s1;

        float m0 = y40, m1 = y41;
        #pragma unroll
        for (int o = 16; o >= 1; o >>= 1) {
            m0 = fmaxf(m0, __shfl_xor(m0, o));
            m1 = fmaxf(m1, __shfl_xor(m1, o));
        }
        float e0 = __expf(y40 - m0), e1 = __expf(y41 - m1);
        float t0 = e0, t1 = e1;
        #pragma unroll
        for (int o = 16; o >= 1; o >>= 1) {
            t0 += __shfl_xor(t0, o);
            t1 += __shfl_xor(t1, o);
        }
        if (h == 0) {
            gS[(r0 + 0) * 32 + k] = e0 / t0;
            gS[(r0 + 1) * 32 + k] = e1 / t1;
        }
    }
    __syncthreads();

    // ---- per-block gamma sums -> Sp[k][blk] ----
    if (tid < 32) {
        float s0 = 0.f, s1 = 0.f, s2 = 0.f, s3 = 0.f;
        #pragma unroll
        for (int r = 0; r < 32; r += 4) {
            s0 += gS[(r + 0) * 32 + tid];
            s1 += gS[(r + 1) * 32 + tid];
            s2 += gS[(r + 2) * 32 + tid];
            s3 += gS[(r + 3) * 32 + tid];
        }
        Sp[tid * 256 + blk] = (s0 + s1) + (s2 + s3);
    }

    // ---- accumulate: thread = (kg: 2 k's, d4: 4 d's); bf16 nt P stores ----
    {
        int kg = tid >> 6;                   // 0..15 -> k in {2kg, 2kg+1}
        int d4 = tid & 63;                   // float4 column (4 consecutive d)
        const f4x* xl4 = (const f4x*)xS4;    // [r*64 + d4]
        const float2* gS2 = (const float2*)gS;

        f4x aG0 = {0.f, 0.f, 0.f, 0.f}, aH0 = aG0, aG1 = aG0, aH1 = aG0;

        #pragma unroll 4
        for (int r = 0; r < 32; ++r) {
            f4x xv = xl4[r * 64 + d4];
            f4x xx = xv * xv;
            float2 g2 = gS2[r * 16 + kg];    // wave-uniform -> broadcast
            aG0 += g2.x * xv;  aH0 += g2.x * xx;
            aG1 += g2.y * xv;  aH1 += g2.y * xx;
        }

        unsigned short* Pb = (unsigned short*)ws;
        int k0 = kg * 2, k1 = k0 + 1;
        size_t dd = (size_t)4 * d4;
        nt_store_bf4(Pb + ((size_t)(k0 * 2 + 0) * 256 + blk) * 256 + dd, aG0);
        nt_store_bf4(Pb + ((size_t)(k0 * 2 + 1) * 256 + blk) * 256 + dd, aH0);
        nt_store_bf4(Pb + ((size_t)(k1 * 2 + 0) * 256 + blk) * 256 + dd, aG1);
        nt_store_bf4(Pb + ((size_t)(k1 * 2 + 1) * 256 + blk) * 256 + dd, aH1);
    }
}

// K2 (final): 512 blocks x 256 thr; block (k,gh,c) reduces its 32-row chunk of
// bf16 P, then atomically adds its FINAL-SCALED contribution to out (epilogue is
// linear in the chunk partials). Blocks (k,gh=0,c=0) also fold in the sv terms.
// No P2, no K3, no device-side sync — stream order only.
__global__ __launch_bounds__(256) void red_final(const float* __restrict__ w,
                                                 const float* __restrict__ b,
                                                 const float* __restrict__ ws,
                                                 float* __restrict__ out) {
    const unsigned short* Pb = (const unsigned short*)ws;
    const float* Sp = ws + SP_OFF;
    __shared__ __align__(16) f4x sT[512];
    __shared__ float sred[4];
    int tid = threadIdx.x;
    int cb = tid & 31;                       // bf16x8 column group (8 d's)
    int g  = tid >> 5;                       // rowgroup 0..7 (4 rows each)
    int bid = blockIdx.x;
    int k  = bid >> 4;
    int gh = (bid >> 3) & 1;
    int c  = bid & 7;

    // ---- chunk reduction: rows [bid*32, bid*32+32) of the [16384][256] view ----
    const u4x* p = (const u4x*)(Pb + ((size_t)bid * 32 + g * 4) * 256 + cb * 8);
    f4x a0 = {0.f, 0.f, 0.f, 0.f}, a1 = a0;
    #pragma unroll
    for (int j = 0; j < 4; ++j) {
        u4x v = __builtin_nontemporal_load(&p[(size_t)j * 32]);  // row = 32 u4x
        a0.x += bflo(v.x); a0.y += bfhi(v.x); a0.z += bflo(v.y); a0.w += bfhi(v.y);
        a1.x += bflo(v.z); a1.y += bfhi(v.z); a1.z += bflo(v.w); a1.w += bfhi(v.w);
    }
    sT[(g * 32 + cb) * 2 + 0] = a0;          // float layout: sTf[g*256 + d]
    sT[(g * 32 + cb) * 2 + 1] = a1;
    __syncthreads();

    // ---- per-thread d: combine 8 rowgroups (stride-1, conflict-free) ----
    int d = tid;
    const float* sTf = (const float*)sT;
    float s = 0.f;
    #pragma unroll
    for (int j = 0; j < 8; ++j) s += sTf[j * 256 + d];

    int idx = k * Dd + d;
    float wv = w[idx], bv = b[idx];
    const float invN = 1.0f / 8192.0f;
    const float c2 = 0.70710678118654752440f * invN;   // 1/(sqrt(2)*N)
    float w2 = wv * wv;

    float sg_c, mu_c;
    if (gh == 0) {                            // s = G-chunk
        mu_c = wv * s * invN;
        sg_c = w2 * 2.0f * bv * s * c2;
    } else {                                  // s = H-chunk
        mu_c = 0.f;
        sg_c = w2 * s * c2;
    }

    if (gh == 0 && c == 0) {                  // fold in the sv terms (once per k)
        float svp = Sp[k * 256 + tid];
        #pragma unroll
        for (int o = 32; o >= 1; o >>= 1) svp += __shfl_xor(svp, o);
        if ((tid & 63) == 0) sred[tid >> 6] = svp;
        __syncthreads();
        float sv = (sred[0] + sred[1]) + (sred[2] + sred[3]);
        sg_c += (w2 * bv * bv - 1.0f) * sv * c2;
        mu_c += wv * bv * sv * invN;
    }

    atomicAdd(&out[idx], sg_c);               // sigma_part
    if (gh == 0) atomicAdd(&out[Kk * Dd + idx], mu_c);   // mu_part
}

extern "C" void kernel_launch(void* const* d_in, const int* in_sizes, int n_in,
                              void* d_out, int out_size, void* d_ws, size_t ws_size,
                              hipStream_t stream) {
    const float* x = (const float*)d_in[0];
    const float* w = (const float*)d_in[1];
    const float* b = (const float*)d_in[2];
    float* out = (float*)d_out;
    float* ws = (float*)d_ws;

    hipLaunchKernelGGL(fused_kernel, dim3(256), dim3(1024), 0, stream, x, w, b, ws, out);
    hipLaunchKernelGGL(red_final,    dim3(512), dim3(256),  0, stream, w, b, ws, out);
}